// Round 15
// baseline (136.460 us; speedup 1.0000x reference)
//
#include <hip/hip_runtime.h>
#include <math.h>

typedef _Float16 half8 __attribute__((ext_vector_type(8)));
typedef __fp16   fp16x2 __attribute__((ext_vector_type(2)));  // cvt_pkrtz's return type
typedef float f32x4 __attribute__((ext_vector_type(4)));

// Branchless exact-grade GELU: x*0.5*(1+erf(x/sqrt(2))) with A&S 7.1.26 erf,
// |erf err| <= 1.5e-7 (vs output threshold 2.47e-2).
__device__ __forceinline__ float gelu_f(float v) {
    float y  = v * 0.70710678118654752f;
    float ay = __builtin_fabsf(y);
    float t  = __builtin_amdgcn_rcpf(__builtin_fmaf(0.3275911f, ay, 1.0f));
    float p  = __builtin_fmaf(t, 1.061405429f, -1.453152027f);
    p = __builtin_fmaf(p, t, 1.421413741f);
    p = __builtin_fmaf(p, t, -0.284496736f);
    p = __builtin_fmaf(p, t, 0.254829592f);
    p = p * t;
    float e  = __builtin_amdgcn_exp2f(ay * ay * -1.4426950408889634f);
    float er = __builtin_fmaf(-p, e, 1.0f);        // erf(|y|), saturates to 1
    er = __builtin_copysignf(er, v);               // restore sign
    float hv = 0.5f * v;
    return __builtin_fmaf(hv, er, hv);
}

// Sum over the 16 lanes of a DPP row (our c index) via row_ror rotate-reduce.
// Pure VALU -- replaces __shfl_xor's ds_swizzle (LDS pipe) with DPP adds.
__device__ __forceinline__ float rowsum16(float v) {
    int t;
    t = __builtin_amdgcn_update_dpp(0, __float_as_int(v), 0x121, 0xf, 0xf, true); // ror:1
    v += __int_as_float(t);
    t = __builtin_amdgcn_update_dpp(0, __float_as_int(v), 0x122, 0xf, 0xf, true); // ror:2
    v += __int_as_float(t);
    t = __builtin_amdgcn_update_dpp(0, __float_as_int(v), 0x124, 0xf, 0xf, true); // ror:4
    v += __int_as_float(t);
    t = __builtin_amdgcn_update_dpp(0, __float_as_int(v), 0x128, 0xf, 0xf, true); // ror:8
    v += __int_as_float(t);
    return v;
}

#define MFMA16(A, B, C) __builtin_amdgcn_mfma_f32_16x16x32_f16((A), (B), (C), 0, 0, 0)

union H8u { half8 h8; fp16x2 h2[4]; };

// One wave owns TWO 16-row tiles per iteration, phase-major (layer1 A,B ->
// layer2 A,B -> res A,B).  fp16 MFMA, fp32 accum.  A-frag: row = lane&15,
// k = 32*s + 8*(lane>>4) + j.  C-layout (m89): col = lane&15, row =
// 4*(lane>>4) + reg.
//
// r14 post-mortem: 4 -> 6 waves/SIMD gave ZERO speedup -> per-CU pipe
// saturated, not occupancy.  DS accounting: 61 LDS-pipe ops/tile (18 wtab
// re-reads + 24 staging writes + 3 reads + 16 ds_swizzle shuffles) ~ 45us
// pipe-busy ~ the wall time.  This round cuts DS/pair 122 -> 72:
//  (1) DPP row_ror rotate-reduce epilogue (VALU, off the LDS pipe),
//  (2) wtab frags read once per PAIR (phase-major dual tile; r9's dual-tile
//      is now viable because weights live in LDS, not 72 registers),
//  (3) dual-tile ILP overlaps A's memory latency with B's compute.
__global__ __launch_bounds__(512, 4) void mlp_mfma_kernel(
    const float* __restrict__ x,
    const float* __restrict__ alpha,
    const float* __restrict__ beta,
    const float* __restrict__ gamma,
    const float* __restrict__ gscal,
    const float* __restrict__ W1, const float* __restrict__ b1,
    const float* __restrict__ W2, const float* __restrict__ b2,
    const float* __restrict__ Wres, const float* __restrict__ bres,
    const float* __restrict__ W6, const float* __restrict__ b6,
    float* __restrict__ out, int B)
{
    const int lane = threadIdx.x & 63;
    const int wid  = threadIdx.x >> 6;   // 0..7
    const int c    = lane & 15;   // col (N) index / A-row index
    const int g    = lane >> 4;   // k-group 0..3

    // Weight-fragment table (block-shared): frags 0..11 = W1[t*3+s],
    // 12..15 = W2[12+t*2+s], 16..17 = Wres[16+t].  18 frags x 64 lanes x 16B.
    __shared__ __align__(16) _Float16 wtab[18 * 512];
    // per-wave, per-tile activation staging
    __shared__ __align__(16) _Float16 h1buf[8][2][16 * 72];
    __shared__ __align__(16) _Float16 h2buf[8][2][16 * 40];
    _Float16* __restrict__ h1A = h1buf[wid][0];
    _Float16* __restrict__ h1B = h1buf[wid][1];
    _Float16* __restrict__ h2A = h2buf[wid][0];
    _Float16* __restrict__ h2B = h2buf[wid][1];

    // ---- build weight tables once (wave 0) ----
    if (wid == 0) {
        float gm[8];
        #pragma unroll
        for (int j = 0; j < 8; ++j) {
            int k  = 8 * g + j;
            int kc = k < 3 ? 3 : (k > 22 ? 22 : k);     // clamp: safe load
            float gv = gamma[kc];
            gm[j] = (k >= 3 && k < 23) ? gv : 1.0f;
        }
        #pragma unroll
        for (int t = 0; t < 4; ++t)
            #pragma unroll
            for (int s = 0; s < 3; ++s)
                #pragma unroll
                for (int j = 0; j < 8; ++j) {
                    int k  = 32 * s + 8 * g + j;
                    int kc = k < 73 ? k : 72;           // clamp: no OOB load
                    float v = W1[(16 * t + c) * 73 + kc];
                    if (s == 0) v *= gm[j];             // gamma folded into s=0
                    wtab[(t * 3 + s) * 512 + lane * 8 + j] =
                        (k < 73) ? (_Float16)v : (_Float16)0.f;
                }
        #pragma unroll
        for (int t = 0; t < 2; ++t)
            #pragma unroll
            for (int s = 0; s < 2; ++s)
                #pragma unroll
                for (int j = 0; j < 8; ++j)
                    wtab[(12 + t * 2 + s) * 512 + lane * 8 + j] =
                        (_Float16)W2[(16 * t + c) * 64 + 32 * s + 8 * g + j];
        #pragma unroll
        for (int t = 0; t < 2; ++t)
            #pragma unroll
            for (int j = 0; j < 8; ++j)
                wtab[(16 + t) * 512 + lane * 8 + j] =
                    (_Float16)Wres[(16 * t + c) * 32 + 8 * g + j];
    }

    // biases / final weights stay in registers (10 regs)
    float b1f[4], b2f[2], brf[2], w6f[2];
    #pragma unroll
    for (int t = 0; t < 4; ++t) b1f[t] = b1[16 * t + c];
    #pragma unroll
    for (int t = 0; t < 2; ++t) { b2f[t] = b2[16 * t + c]; brf[t] = bres[16 * t + c]; w6f[t] = W6[16 * t + c]; }
    const float b6g = b6[0] + gscal[0];

    __syncthreads();   // table visible to all waves (once, outside hot loop)

    const _Float16* wt = wtab + lane * 8;   // shared vaddr; frag f at +f*512

    const int npairs = (B >> 4) >> 1;   // 31250 pairs of 16-row tiles
    const int totw   = gridDim.x * 8;
    for (int q = blockIdx.x * 8 + wid; q < npairs; q += totw) {
        const int RA = q << 5;          // tile A rows RA..RA+15, tile B +16
        const float* __restrict__ xrA = x + (size_t)(RA + c) * 73;
        const float* __restrict__ xrB = xrA + 16 * 73;

        // ---- x loads for BOTH tiles (all independent, in flight together) ----
        float Axv0[8], Axv1[8], Axv2[8], Bxv0[8], Bxv1[8], Bxv2[8];
        #pragma unroll
        for (int j = 0; j < 8; ++j) Axv0[j] = xrA[8 * g + j];
        #pragma unroll
        for (int j = 0; j < 8; ++j) Bxv0[j] = xrB[8 * g + j];
        #pragma unroll
        for (int j = 0; j < 8; ++j) Axv1[j] = xrA[32 + 8 * g + j];
        #pragma unroll
        for (int j = 0; j < 8; ++j) Bxv1[j] = xrB[32 + 8 * g + j];
        #pragma unroll
        for (int j = 0; j < 8; ++j) {
            int k = 64 + 8 * g + j;
            float vA = xrA[k < 73 ? k : 72];
            float vB = xrB[k < 73 ? k : 72];
            Axv2[j] = (k < 73) ? vA : 0.f;
            Bxv2[j] = (k < 73) ? vB : 0.f;
        }

        // ---- embed gathers for both tiles (latencies overlap) ----
        float Axa = 0.f, Axb = 0.f, Bxa = 0.f, Bxb = 0.f;
        if (g == 0) {
            Axa = alpha[(int)Axv0[0]]; Axb = beta[(int)Axv0[1]];
            Bxa = alpha[(int)Bxv0[0]]; Bxb = beta[(int)Bxv0[1]];
        }

        // ---- pack A-frags for both tiles (kills the 48 raw xv regs) ----
        H8u Aa0, Aa1, Aa2, Ba0, Ba1, Ba2;
        #pragma unroll
        for (int j = 0; j < 4; ++j) {
            Aa1.h2[j] = __builtin_amdgcn_cvt_pkrtz(Axv1[2 * j], Axv1[2 * j + 1]);
            Ba1.h2[j] = __builtin_amdgcn_cvt_pkrtz(Bxv1[2 * j], Bxv1[2 * j + 1]);
            Aa2.h2[j] = __builtin_amdgcn_cvt_pkrtz(Axv2[2 * j], Axv2[2 * j + 1]);
            Ba2.h2[j] = __builtin_amdgcn_cvt_pkrtz(Bxv2[2 * j], Bxv2[2 * j + 1]);
            Aa0.h2[j] = __builtin_amdgcn_cvt_pkrtz(Axv0[2 * j], Axv0[2 * j + 1]);
            Ba0.h2[j] = __builtin_amdgcn_cvt_pkrtz(Bxv0[2 * j], Bxv0[2 * j + 1]);
        }
        {
            fp16x2 weA = __builtin_amdgcn_cvt_pkrtz(Axa, Axb);
            fp16x2 weB = __builtin_amdgcn_cvt_pkrtz(Bxa, Bxb);
            if (g == 0) { Aa0.h2[0] = weA; Ba0.h2[0] = weB; }
        }

        // ---- layer 1 phase: W1 frags read ONCE, used for A and B ----
        f32x4 accA[4], accB[4];
        #pragma unroll
        for (int t = 0; t < 4; ++t) {
            f32x4 z = { b1f[t], b1f[t], b1f[t], b1f[t] };
            accA[t] = z; accB[t] = z;
        }
        #pragma unroll
        for (int t = 0; t < 4; ++t) {
            half8 w1 = *reinterpret_cast<const half8*>(wt + (t * 3 + 1) * 512);
            accA[t] = MFMA16(Aa1.h8, w1, accA[t]);
            accB[t] = MFMA16(Ba1.h8, w1, accB[t]);
        }
        #pragma unroll
        for (int t = 0; t < 4; ++t) {
            half8 w2_ = *reinterpret_cast<const half8*>(wt + (t * 3 + 2) * 512);
            accA[t] = MFMA16(Aa2.h8, w2_, accA[t]);
            accB[t] = MFMA16(Ba2.h8, w2_, accB[t]);
        }
        #pragma unroll
        for (int t = 0; t < 4; ++t) {
            half8 w0 = *reinterpret_cast<const half8*>(wt + (t * 3 + 0) * 512);
            accA[t] = MFMA16(Aa0.h8, w0, accA[t]);
            accB[t] = MFMA16(Ba0.h8, w0, accB[t]);
        }

        // GELU -> h1 to LDS (row = 4g+r, col = 16t+c, stride 72)
        #pragma unroll
        for (int t = 0; t < 4; ++t)
            #pragma unroll
            for (int r = 0; r < 4; ++r) {
                h1A[(4 * g + r) * 72 + 16 * t + c] = (_Float16)gelu_f(accA[t][r]);
                h1B[(4 * g + r) * 72 + 16 * t + c] = (_Float16)gelu_f(accB[t][r]);
            }

        asm volatile("s_waitcnt lgkmcnt(0)" ::: "memory");

        // ---- layer 2 phase: w2f read once, used for A and B ----
        half8 Af0 = *reinterpret_cast<const half8*>(&h1A[c * 72 + 8 * g]);
        half8 Af1 = *reinterpret_cast<const half8*>(&h1A[c * 72 + 32 + 8 * g]);
        half8 Bf0 = *reinterpret_cast<const half8*>(&h1B[c * 72 + 8 * g]);
        half8 Bf1 = *reinterpret_cast<const half8*>(&h1B[c * 72 + 32 + 8 * g]);
        f32x4 ac2A[2], ac2B[2];
        #pragma unroll
        for (int t = 0; t < 2; ++t) {
            half8 wA = *reinterpret_cast<const half8*>(wt + (12 + t * 2) * 512);
            half8 wB = *reinterpret_cast<const half8*>(wt + (13 + t * 2) * 512);
            f32x4 z = { b2f[t], b2f[t], b2f[t], b2f[t] };
            f32x4 zA = MFMA16(Af0, wA, z);
            f32x4 zB = MFMA16(Bf0, wA, z);
            ac2A[t] = MFMA16(Af1, wB, zA);
            ac2B[t] = MFMA16(Bf1, wB, zB);
        }
        float h2cA[2][4], h2cB[2][4];
        #pragma unroll
        for (int t = 0; t < 2; ++t)
            #pragma unroll
            for (int r = 0; r < 4; ++r) {
                h2cA[t][r] = gelu_f(ac2A[t][r]);
                h2cB[t][r] = gelu_f(ac2B[t][r]);
            }

        // h2 to LDS (stride 40)
        #pragma unroll
        for (int t = 0; t < 2; ++t)
            #pragma unroll
            for (int r = 0; r < 4; ++r) {
                h2A[(4 * g + r) * 40 + 16 * t + c] = (_Float16)h2cA[t][r];
                h2B[(4 * g + r) * 40 + 16 * t + c] = (_Float16)h2cB[t][r];
            }

        asm volatile("s_waitcnt lgkmcnt(0)" ::: "memory");

        // ---- residual phase: wrf read once ----
        half8 ArA = *reinterpret_cast<const half8*>(&h2A[c * 40 + 8 * g]);
        half8 ArB = *reinterpret_cast<const half8*>(&h2B[c * 40 + 8 * g]);
        f32x4 acrA[2], acrB[2];
        #pragma unroll
        for (int t = 0; t < 2; ++t) {
            half8 wr = *reinterpret_cast<const half8*>(wt + (16 + t) * 512);
            f32x4 zA = { brf[t] + h2cA[t][0], brf[t] + h2cA[t][1],
                         brf[t] + h2cA[t][2], brf[t] + h2cA[t][3] };
            f32x4 zB = { brf[t] + h2cB[t][0], brf[t] + h2cB[t][1],
                         brf[t] + h2cB[t][2], brf[t] + h2cB[t][3] };
            acrA[t] = MFMA16(ArA, wr, zA);
            acrB[t] = MFMA16(ArB, wr, zB);
        }

        // ---- final 32->1: per-lane partial, DPP rotate-reduce over c ----
        f32x4 pA, pB;
        #pragma unroll
        for (int r = 0; r < 4; ++r) {
            pA[r] = rowsum16(gelu_f(acrA[0][r]) * w6f[0] + gelu_f(acrA[1][r]) * w6f[1]);
            pB[r] = rowsum16(gelu_f(acrB[0][r]) * w6f[0] + gelu_f(acrB[1][r]) * w6f[1]);
        }
        if (c == 0) {
            f32x4 oA = { pA[0] + b6g, pA[1] + b6g, pA[2] + b6g, pA[3] + b6g };
            f32x4 oB = { pB[0] + b6g, pB[1] + b6g, pB[2] + b6g, pB[3] + b6g };
            *reinterpret_cast<f32x4*>(out + RA + 4 * g)      = oA;
            *reinterpret_cast<f32x4*>(out + RA + 16 + 4 * g) = oB;
        }
    }
}

extern "C" void kernel_launch(void* const* d_in, const int* in_sizes, int n_in,
                              void* d_out, int out_size, void* d_ws, size_t ws_size,
                              hipStream_t stream) {
    const float* x     = (const float*)d_in[0];
    const float* alpha = (const float*)d_in[1];
    const float* beta  = (const float*)d_in[2];
    const float* gamma = (const float*)d_in[3];
    const float* g     = (const float*)d_in[4];
    const float* W1    = (const float*)d_in[5];
    const float* b1    = (const float*)d_in[6];
    const float* W2    = (const float*)d_in[7];
    const float* b2    = (const float*)d_in[8];
    const float* Wres  = (const float*)d_in[9];
    const float* bres  = (const float*)d_in[10];
    const float* W6    = (const float*)d_in[11];
    const float* b6    = (const float*)d_in[12];
    float* out = (float*)d_out;

    int B = out_size;          // 1e6 rows; divisible by 32
    // 512 blocks x 512 threads: LDS 75776 B/block -> 2 blocks/CU (151.5KB),
    // 16 waves/CU.  31250 pairs over 4096 waves = ~7.6 pairs/wave.
    int nblocks = 512;
    mlp_mfma_kernel<<<nblocks, 512, 0, stream>>>(x, alpha, beta, gamma, g,
                                                 W1, b1, W2, b2, Wres, bres,
                                                 W6, b6, out, B);
}

// Round 16
// 98.820 us; speedup vs baseline: 1.3809x; 1.3809x over previous
//
#include <hip/hip_runtime.h>
#include <math.h>

typedef _Float16 half8 __attribute__((ext_vector_type(8)));
typedef __fp16   fp16x2 __attribute__((ext_vector_type(2)));  // cvt_pkrtz's return type
typedef float f32x4 __attribute__((ext_vector_type(4)));

// Branchless exact-grade GELU: x*0.5*(1+erf(x/sqrt(2))) with A&S 7.1.26 erf,
// |erf err| <= 1.5e-7 (vs output threshold 2.47e-2).
__device__ __forceinline__ float gelu_f(float v) {
    float y  = v * 0.70710678118654752f;
    float ay = __builtin_fabsf(y);
    float t  = __builtin_amdgcn_rcpf(__builtin_fmaf(0.3275911f, ay, 1.0f));
    float p  = __builtin_fmaf(t, 1.061405429f, -1.453152027f);
    p = __builtin_fmaf(p, t, 1.421413741f);
    p = __builtin_fmaf(p, t, -0.284496736f);
    p = __builtin_fmaf(p, t, 0.254829592f);
    p = p * t;
    float e  = __builtin_amdgcn_exp2f(ay * ay * -1.4426950408889634f);
    float er = __builtin_fmaf(-p, e, 1.0f);        // erf(|y|), saturates to 1
    er = __builtin_copysignf(er, v);               // restore sign
    float hv = 0.5f * v;
    return __builtin_fmaf(hv, er, hv);
}

// Sum over the 16 lanes of a DPP row (our c index) via row_ror rotate-reduce.
// Pure VALU -- keeps the reduction off the LDS pipe (vs __shfl_xor/ds_swizzle).
__device__ __forceinline__ float rowsum16(float v) {
    int t;
    t = __builtin_amdgcn_update_dpp(0, __float_as_int(v), 0x121, 0xf, 0xf, true); // ror:1
    v += __int_as_float(t);
    t = __builtin_amdgcn_update_dpp(0, __float_as_int(v), 0x122, 0xf, 0xf, true); // ror:2
    v += __int_as_float(t);
    t = __builtin_amdgcn_update_dpp(0, __float_as_int(v), 0x124, 0xf, 0xf, true); // ror:4
    v += __int_as_float(t);
    t = __builtin_amdgcn_update_dpp(0, __float_as_int(v), 0x128, 0xf, 0xf, true); // ror:8
    v += __int_as_float(t);
    return v;
}

#define MFMA16(A, B, C) __builtin_amdgcn_mfma_f32_16x16x32_f16((A), (B), (C), 0, 0, 0)

union H8u { half8 h8; fp16x2 h2[4]; };

// One wave owns a 16-row tile end-to-end.  fp16 MFMA, fp32 accum.
// A-frag: row = lane&15, k = 32*s + 8*(lane>>4) + j.  C-layout (m89):
// col = lane&15, row = 4*(lane>>4) + reg.
//
// r14 post-mortem: 4 and 6 waves/SIMD give the SAME 97us -> a per-CU pipe
// binds, and it isn't VALU (42% ~ 41us), LDS (~48us) or HBM (26%).  Suspect:
// the vector-memory address unit.  Old per-lane x loads (lane (c,g) reads
// (R0+c)*292 + 32g + 4j) scatter each wave-load over ~32 cache-line segments
// -> ~770 TA-cyc/tile -> ~82us/CU, matching the floor.
//
// Fix: COALESCED x staging.  The 16-row tile = 4672 contiguous bytes; 19
// coalesced dword loads (lane i <- element 64j+i, ~2 segments each), cvt to
// fp16, ds_write_b16 into a per-wave [16][96] buffer (consecutive lanes ->
// consecutive halves = 2-way bank alias = free).  Frag reads become 3
// aligned ds_read_b128; the 12 cvt_pkrtz per tile disappear.  Cols 73..95
// zeroed once (MFMA k-pad; B-side is already zero but NaN*0 risk).  Embed
// indices still read as exact f32 (fp16 rounds ints > 2048).  Also: DPP
// rowsum epilogue (LDS-pipe -> VALU) and W2/Wres frags hoisted to regs.
__global__ __launch_bounds__(512, 4) void mlp_mfma_kernel(
    const float* __restrict__ x,
    const float* __restrict__ alpha,
    const float* __restrict__ beta,
    const float* __restrict__ gamma,
    const float* __restrict__ gscal,
    const float* __restrict__ W1, const float* __restrict__ b1,
    const float* __restrict__ W2, const float* __restrict__ b2,
    const float* __restrict__ Wres, const float* __restrict__ bres,
    const float* __restrict__ W6, const float* __restrict__ b6,
    float* __restrict__ out, int B)
{
    const int lane = threadIdx.x & 63;
    const int wid  = threadIdx.x >> 6;   // 0..7
    const int c    = lane & 15;   // col (N) index / A-row index
    const int g    = lane >> 4;   // k-group 0..3

    // Weight-fragment table (block-shared): frags 0..11 = W1[t*3+s],
    // 12..15 = W2, 16..17 = Wres.  18 frags x 64 lanes x 16B.
    __shared__ __align__(16) _Float16 wtab[18 * 512];
    // per-wave coalesced x staging: 16 rows x 96 halves (pitch 192B, 16B-aligned)
    __shared__ __align__(16) _Float16 xstage[8][16 * 96];
    // per-wave activation staging
    __shared__ __align__(16) _Float16 h1buf[8][16 * 72];
    __shared__ __align__(16) _Float16 h2buf[8][16 * 40];
    _Float16* __restrict__ xs  = xstage[wid];
    _Float16* __restrict__ h1b = h1buf[wid];
    _Float16* __restrict__ h2b = h2buf[wid];

    // ---- build weight tables once (wave 0) ----
    if (wid == 0) {
        float gm[8];
        #pragma unroll
        for (int j = 0; j < 8; ++j) {
            int k  = 8 * g + j;
            int kc = k < 3 ? 3 : (k > 22 ? 22 : k);     // clamp: safe load
            float gv = gamma[kc];
            gm[j] = (k >= 3 && k < 23) ? gv : 1.0f;
        }
        #pragma unroll
        for (int t = 0; t < 4; ++t)
            #pragma unroll
            for (int s = 0; s < 3; ++s)
                #pragma unroll
                for (int j = 0; j < 8; ++j) {
                    int k  = 32 * s + 8 * g + j;
                    int kc = k < 73 ? k : 72;           // clamp: no OOB load
                    float v = W1[(16 * t + c) * 73 + kc];
                    if (s == 0) v *= gm[j];             // gamma folded into s=0
                    wtab[(t * 3 + s) * 512 + lane * 8 + j] =
                        (k < 73) ? (_Float16)v : (_Float16)0.f;
                }
        #pragma unroll
        for (int t = 0; t < 2; ++t)
            #pragma unroll
            for (int s = 0; s < 2; ++s)
                #pragma unroll
                for (int j = 0; j < 8; ++j)
                    wtab[(12 + t * 2 + s) * 512 + lane * 8 + j] =
                        (_Float16)W2[(16 * t + c) * 64 + 32 * s + 8 * g + j];
        #pragma unroll
        for (int t = 0; t < 2; ++t)
            #pragma unroll
            for (int j = 0; j < 8; ++j)
                wtab[(16 + t) * 512 + lane * 8 + j] =
                    (_Float16)Wres[(16 * t + c) * 32 + 8 * g + j];
    }

    // zero the k-pad (cols 73..95) of this wave's xstage, once
    for (int idx = lane; idx < 16 * 23; idx += 64) {
        int r_ = idx / 23;
        int c_ = 73 + (idx - r_ * 23);
        xs[r_ * 96 + c_] = (_Float16)0.f;
    }

    // biases / final weights in registers (10 regs)
    float b1f[4], b2f[2], brf[2], w6f[2];
    #pragma unroll
    for (int t = 0; t < 4; ++t) b1f[t] = b1[16 * t + c];
    #pragma unroll
    for (int t = 0; t < 2; ++t) { b2f[t] = b2[16 * t + c]; brf[t] = bres[16 * t + c]; w6f[t] = W6[16 * t + c]; }
    const float b6g = b6[0] + gscal[0];

    __syncthreads();   // wtab visible to all waves

    const _Float16* wt = wtab + lane * 8;   // shared vaddr; frag f at +f*512

    // W2 / Wres frags hoisted to registers (block-invariant; -6 LDS reads/tile)
    half8 w2f[2][2], wrf[2];
    #pragma unroll
    for (int t = 0; t < 2; ++t)
        #pragma unroll
        for (int s = 0; s < 2; ++s)
            w2f[t][s] = *reinterpret_cast<const half8*>(wt + (12 + t * 2 + s) * 512);
    #pragma unroll
    for (int t = 0; t < 2; ++t)
        wrf[t] = *reinterpret_cast<const half8*>(wt + (16 + t) * 512);

    const int ntiles = B >> 4;
    const int totw   = gridDim.x * 8;
    for (int tile = blockIdx.x * 8 + wid; tile < ntiles; tile += totw) {
        const int R0 = tile << 4;
        const float* __restrict__ xt = x + (size_t)R0 * 73;

        // ---- embed chain first (f32-exact indices; g==0 lanes only) ----
        float x0 = 0.f, x1 = 0.f, xa = 0.f, xb = 0.f;
        if (g == 0) {
            x0 = xt[c * 73];
            x1 = xt[c * 73 + 1];
        }

        // ---- coalesced tile load: 19 x global_load_dword, lane i <- elem 64j+i ----
        float lf[19];
        #pragma unroll
        for (int j = 0; j < 18; ++j) lf[j] = xt[64 * j + lane];
        lf[18] = (lane < 16) ? xt[64 * 18 + lane] : 0.f;

        if (g == 0) {
            xa = alpha[(int)x0];
            xb = beta[(int)x1];
        }

        // ---- stage to LDS fp16 (incremental row/col; consecutive lanes ->
        //      consecutive halves: conflict-free) ----
        {
            int row = 0, col = lane;   // element e = 64j + lane; e<73 at j=0
            #pragma unroll
            for (int j = 0; j < 19; ++j) {
                if (j < 18 || lane < 16)
                    xs[row * 96 + col] = (_Float16)lf[j];
                col += 64;
                int wrap = (col >= 73) ? 1 : 0;
                col -= wrap ? 73 : 0;
                row += wrap;
            }
        }

        asm volatile("s_waitcnt lgkmcnt(0)" ::: "memory");

        // ---- A-frags straight from staged fp16 (aligned b128 reads) ----
        const _Float16* xrow = xs + c * 96;
        half8 a1f = *reinterpret_cast<const half8*>(xrow + 32 + 8 * g);
        half8 a2f = *reinterpret_cast<const half8*>(xrow + 64 + 8 * g);
        H8u a0u;
        a0u.h8 = *reinterpret_cast<const half8*>(xrow + 8 * g);
        {
            fp16x2 we = __builtin_amdgcn_cvt_pkrtz(xa, xb);
            if (g == 0) a0u.h2[0] = we;   // embed cols 0/1 on g==0 lanes
        }

        // ---- layer 1: 73->64 (W1 frags from LDS; k0 last to cover gathers) ----
        f32x4 acc[4];
        #pragma unroll
        for (int t = 0; t < 4; ++t) { f32x4 z = { b1f[t], b1f[t], b1f[t], b1f[t] }; acc[t] = z; }
        #pragma unroll
        for (int t = 0; t < 4; ++t)
            acc[t] = MFMA16(a1f, *reinterpret_cast<const half8*>(wt + (t * 3 + 1) * 512), acc[t]);
        #pragma unroll
        for (int t = 0; t < 4; ++t)
            acc[t] = MFMA16(a2f, *reinterpret_cast<const half8*>(wt + (t * 3 + 2) * 512), acc[t]);
        #pragma unroll
        for (int t = 0; t < 4; ++t)
            acc[t] = MFMA16(a0u.h8, *reinterpret_cast<const half8*>(wt + (t * 3 + 0) * 512), acc[t]);

        // GELU -> h1 to LDS (row = 4g+r, col = 16t+c, stride 72)
        #pragma unroll
        for (int t = 0; t < 4; ++t)
            #pragma unroll
            for (int r = 0; r < 4; ++r)
                h1b[(4 * g + r) * 72 + 16 * t + c] = (_Float16)gelu_f(acc[t][r]);

        asm volatile("s_waitcnt lgkmcnt(0)" ::: "memory");

        // ---- layer 2: 64->32 (weights in regs) ----
        half8 a2f0 = *reinterpret_cast<const half8*>(&h1b[c * 72 + 8 * g]);
        half8 a2f1 = *reinterpret_cast<const half8*>(&h1b[c * 72 + 32 + 8 * g]);
        f32x4 ac2[2];
        #pragma unroll
        for (int t = 0; t < 2; ++t) {
            f32x4 z = { b2f[t], b2f[t], b2f[t], b2f[t] };
            z = MFMA16(a2f0, w2f[t][0], z);
            ac2[t] = MFMA16(a2f1, w2f[t][1], z);
        }
        float h2c[2][4];
        #pragma unroll
        for (int t = 0; t < 2; ++t)
            #pragma unroll
            for (int r = 0; r < 4; ++r)
                h2c[t][r] = gelu_f(ac2[t][r]);

        // h2 to LDS (stride 40)
        #pragma unroll
        for (int t = 0; t < 2; ++t)
            #pragma unroll
            for (int r = 0; r < 4; ++r)
                h2b[(4 * g + r) * 40 + 16 * t + c] = (_Float16)h2c[t][r];

        asm volatile("s_waitcnt lgkmcnt(0)" ::: "memory");

        // ---- residual layer: C-init = bres + h2 (weights in regs) ----
        half8 arf = *reinterpret_cast<const half8*>(&h2b[c * 40 + 8 * g]);
        f32x4 acr[2];
        #pragma unroll
        for (int t = 0; t < 2; ++t) {
            f32x4 z = { brf[t] + h2c[t][0], brf[t] + h2c[t][1],
                        brf[t] + h2c[t][2], brf[t] + h2c[t][3] };
            acr[t] = MFMA16(arf, wrf[t], z);
        }

        // ---- final 32->1: per-lane partial, DPP rotate-reduce over c ----
        f32x4 p;
        #pragma unroll
        for (int r = 0; r < 4; ++r)
            p[r] = rowsum16(gelu_f(acr[0][r]) * w6f[0] + gelu_f(acr[1][r]) * w6f[1]);
        if (c == 0) {
            f32x4 o = { p[0] + b6g, p[1] + b6g, p[2] + b6g, p[3] + b6g };
            *reinterpret_cast<f32x4*>(out + R0 + 4 * g) = o;  // rows R0+4g..+3
        }
    }
}

extern "C" void kernel_launch(void* const* d_in, const int* in_sizes, int n_in,
                              void* d_out, int out_size, void* d_ws, size_t ws_size,
                              hipStream_t stream) {
    const float* x     = (const float*)d_in[0];
    const float* alpha = (const float*)d_in[1];
    const float* beta  = (const float*)d_in[2];
    const float* gamma = (const float*)d_in[3];
    const float* g     = (const float*)d_in[4];
    const float* W1    = (const float*)d_in[5];
    const float* b1    = (const float*)d_in[6];
    const float* W2    = (const float*)d_in[7];
    const float* b2    = (const float*)d_in[8];
    const float* Wres  = (const float*)d_in[9];
    const float* bres  = (const float*)d_in[10];
    const float* W6    = (const float*)d_in[11];
    const float* b6    = (const float*)d_in[12];
    float* out = (float*)d_out;

    int B = out_size;          // 1e6 rows; divisible by 16
    // 512 blocks x 512 threads: LDS 71680 B/block -> 2 blocks/CU (143KB),
    // 16 waves/CU (4/SIMD -- r10/r14 showed >=4 waves is not the limiter).
    int nblocks = 512;
    mlp_mfma_kernel<<<nblocks, 512, 0, stream>>>(x, alpha, beta, gamma, g,
                                                 W1, b1, W2, b2, Wres, bres,
                                                 W6, b6, out, B);
}